// Round 3
// baseline (572.753 us; speedup 1.0000x reference)
//
#include <hip/hip_runtime.h>

// Problem constants (from reference)
#define N0 409600
#define N1 40960
#define N2 4096
#define KF 10          // sampled fanout
#define IN 512
#define HID 128
#define NCLS 64
#define CHUNK 5        // neighbors per load-batch (20 float4 loads in flight)

static __device__ __forceinline__ float4 f4_zero() { return make_float4(0.f, 0.f, 0.f, 0.f); }

// ---------------------------------------------------------------------------
// Kernel 1: fused block 0.   [8 nodes/block, 16 KB LDS, 5120 blocks]
//   agg = mean_k(embed[nbr0] - h0_hist[nbr0]) + agg_h0
//   h   = agg @ W1 + b1                      (512 -> 128)
//   h1p = concat(h, relu(h)) - h1_hist       -> ws [N1, 256]
// Gather is LATENCY-bound (R2: 1.8 TB/s @ 52 VGPR, ~4 loads in flight).
// Fix: per node, hoist all 10 indices to SGPRs (readfirstlane), then issue
// 5-neighbor batches of 20 explicit float4 loads into named registers BEFORE
// accumulating -> ~20 KB in flight per wave; 16 waves/CU via 16 KB LDS.
// ---------------------------------------------------------------------------
__global__ __launch_bounds__(256, 4) void k_block0(
    const float* __restrict__ embed, const float* __restrict__ h0_hist,
    const float* __restrict__ h1_hist, const float* __restrict__ agg_h0,
    const float* __restrict__ W1, const float* __restrict__ b1,
    const int* __restrict__ nbr0, float* __restrict__ h1p)
{
    __shared__ float A[8][IN];           // 16 KB aggregated-activation tile
    const int t = threadIdx.x;
    const int wave = t >> 6;
    const int lane = t & 63;
    const int base_node = blockIdx.x * 8;

    // ---- phase 1: gather + mean + add agg_h0 (wave handles 2 nodes) ----
    #pragma unroll 1
    for (int i = 0; i < 2; ++i) {
        const int nl = wave * 2 + i;
        const int node = base_node + nl;
        const int nb = node * KF;
        const int col = lane * 8;        // 64 lanes x 8 floats = full 512 row
        float4 acc0 = f4_zero(), acc1 = f4_zero();

        // indices -> SGPRs (wave-uniform): frees VGPRs, scalar-base addressing
        int idx[KF];
        #pragma unroll
        for (int j = 0; j < KF; ++j)
            idx[j] = __builtin_amdgcn_readfirstlane(nbr0[nb + j]);

        #pragma unroll 1
        for (int c = 0; c < KF / CHUNK; ++c) {
            // ---- issue all 20 loads of this batch before any use ----
            float4 e0[CHUNK], e1[CHUNK], g0[CHUNK], g1[CHUNK];
            #pragma unroll
            for (int jj = 0; jj < CHUNK; ++jj) {
                const size_t row = (size_t)idx[c * CHUNK + jj];
                const float4* ep = (const float4*)(embed   + row * IN + col);
                const float4* gp = (const float4*)(h0_hist + row * IN + col);
                e0[jj] = ep[0]; e1[jj] = ep[1];
                g0[jj] = gp[0]; g1[jj] = gp[1];
            }
            // ---- accumulate ----
            #pragma unroll
            for (int jj = 0; jj < CHUNK; ++jj) {
                acc0.x += e0[jj].x - g0[jj].x; acc0.y += e0[jj].y - g0[jj].y;
                acc0.z += e0[jj].z - g0[jj].z; acc0.w += e0[jj].w - g0[jj].w;
                acc1.x += e1[jj].x - g1[jj].x; acc1.y += e1[jj].y - g1[jj].y;
                acc1.z += e1[jj].z - g1[jj].z; acc1.w += e1[jj].w - g1[jj].w;
            }
        }

        const float s = 1.0f / (float)KF;
        const float4* ah = (const float4*)(agg_h0 + (size_t)node * IN + col);
        const float4 a0 = ah[0], a1 = ah[1];
        float4 r0, r1;
        r0.x = acc0.x * s + a0.x; r0.y = acc0.y * s + a0.y;
        r0.z = acc0.z * s + a0.z; r0.w = acc0.w * s + a0.w;
        r1.x = acc1.x * s + a1.x; r1.y = acc1.y * s + a1.y;
        r1.z = acc1.z * s + a1.z; r1.w = acc1.w * s + a1.w;
        *(float4*)&A[nl][col]     = r0;
        *(float4*)&A[nl][col + 4] = r1;
    }
    __syncthreads();

    // ---- phase 2: GEMV 512 -> 128 + bias + concat/relu - h1_hist ----
    const int r = t >> 5;          // node row 0..7
    const int c0 = (t & 31) * 4;   // output col group (covers 128)
    float4 acc = f4_zero();

    #pragma unroll 4
    for (int k = 0; k < IN; ++k) {
        const float a = A[r][k];
        const float4 w = *(const float4*)&W1[k * HID + c0];
        acc.x += a * w.x; acc.y += a * w.y;
        acc.z += a * w.z; acc.w += a * w.w;
    }

    const float4 bb = *(const float4*)&b1[c0];
    const int node = base_node + r;
    float4 h;
    h.x = acc.x + bb.x; h.y = acc.y + bb.y;
    h.z = acc.z + bb.z; h.w = acc.w + bb.w;
    const float4 hh0 = *(const float4*)&h1_hist[node * (2 * HID) + c0];
    const float4 hh1 = *(const float4*)&h1_hist[node * (2 * HID) + HID + c0];
    float4 o0, o1;
    o0.x = h.x - hh0.x; o0.y = h.y - hh0.y;
    o0.z = h.z - hh0.z; o0.w = h.w - hh0.w;
    o1.x = fmaxf(h.x, 0.f) - hh1.x; o1.y = fmaxf(h.y, 0.f) - hh1.y;
    o1.z = fmaxf(h.z, 0.f) - hh1.z; o1.w = fmaxf(h.w, 0.f) - hh1.w;
    *(float4*)&h1p[node * (2 * HID) + c0]       = o0;
    *(float4*)&h1p[node * (2 * HID) + HID + c0] = o1;
}

// ---------------------------------------------------------------------------
// Kernel 2: fused block 1.   [8 nodes/block, 512 blocks]
//   agg = mean_k(h1p[nbr1]) + agg_h1 ; out = agg @ W2 + b2   (256 -> 64)
// Same ILP treatment: all 10 row-loads in flight (h1p mostly L2/L3-resident).
// ---------------------------------------------------------------------------
__global__ __launch_bounds__(256, 4) void k_block1(
    const float* __restrict__ h1p, const float* __restrict__ agg_h1,
    const float* __restrict__ W2, const float* __restrict__ b2,
    const int* __restrict__ nbr1, float* __restrict__ out)
{
    __shared__ float B[8][2 * HID + 4];   // pad: kill bank alias on phase-2 reads
    const int t = threadIdx.x;
    const int wave = t >> 6;
    const int lane = t & 63;
    const int base_node = blockIdx.x * 8;

    #pragma unroll 1
    for (int i = 0; i < 2; ++i) {
        const int nl = wave * 2 + i;
        const int node = base_node + nl;
        const int nb = node * KF;
        const int col = lane * 4;  // 64 lanes x 4 floats = full 256 row

        int idx[KF];
        #pragma unroll
        for (int j = 0; j < KF; ++j)
            idx[j] = __builtin_amdgcn_readfirstlane(nbr1[nb + j]);

        float4 v[KF];
        #pragma unroll
        for (int j = 0; j < KF; ++j)
            v[j] = *(const float4*)&h1p[(size_t)idx[j] * (2 * HID) + col];

        float4 acc = f4_zero();
        #pragma unroll
        for (int j = 0; j < KF; ++j) {
            acc.x += v[j].x; acc.y += v[j].y;
            acc.z += v[j].z; acc.w += v[j].w;
        }
        const float s = 1.0f / (float)KF;
        const float4 g = *(const float4*)&agg_h1[(size_t)node * (2 * HID) + col];
        float4 r;
        r.x = acc.x * s + g.x; r.y = acc.y * s + g.y;
        r.z = acc.z * s + g.z; r.w = acc.w * s + g.w;
        *(float4*)&B[nl][col] = r;
    }
    __syncthreads();

    // ---- phase 2: GEMV 256 -> 64 + bias ----
    const int r = t >> 5;          // node row 0..7
    const int c0 = (t & 31) * 2;   // col pair (covers 64)
    float2 acc = make_float2(0.f, 0.f);
    #pragma unroll 4
    for (int k = 0; k < 2 * HID; ++k) {
        const float a = B[r][k];
        const float2 w = *(const float2*)&W2[k * NCLS + c0];
        acc.x += a * w.x; acc.y += a * w.y;
    }
    const float2 bb = *(const float2*)&b2[c0];
    float2 o;
    o.x = acc.x + bb.x; o.y = acc.y + bb.y;
    const int node = base_node + r;
    *(float2*)&out[node * NCLS + c0] = o;
}

extern "C" void kernel_launch(void* const* d_in, const int* in_sizes, int n_in,
                              void* d_out, int out_size, void* d_ws, size_t ws_size,
                              hipStream_t stream) {
    const float* embed   = (const float*)d_in[0];
    const float* h0_hist = (const float*)d_in[1];
    const float* h1_hist = (const float*)d_in[2];
    const float* agg_h0  = (const float*)d_in[3];
    const float* agg_h1  = (const float*)d_in[4];
    const float* W1      = (const float*)d_in[5];
    const float* b1      = (const float*)d_in[6];
    const float* W2      = (const float*)d_in[7];
    const float* b2      = (const float*)d_in[8];
    const int*   nbr0    = (const int*)d_in[9];
    const int*   nbr1    = (const int*)d_in[10];
    float* out = (float*)d_out;

    // ws: h1p [N1, 256] f32 = 41.9 MB
    float* h1p = (float*)d_ws;

    k_block0<<<N1 / 8, 256, 0, stream>>>(embed, h0_hist, h1_hist, agg_h0,
                                         W1, b1, nbr0, h1p);
    k_block1<<<N2 / 8, 256, 0, stream>>>(h1p, agg_h1, W2, b2, nbr1, out);
}

// Round 5
// 442.449 us; speedup vs baseline: 1.2945x; 1.2945x over previous
//
#include <hip/hip_runtime.h>
#include <stdint.h>

// Problem constants (from reference)
#define N0 409600
#define N1 40960
#define N2 4096
#define KF 10          // sampled fanout
#define IN 512
#define HID 128
#define NCLS 64
#define NB 16          // nodes per k_block0 block

static __device__ __forceinline__ float4 f4_zero() { return make_float4(0.f, 0.f, 0.f, 0.f); }

// ---------------------------------------------------------------------------
// One self-contained batch: 10 x global_load_dwordx4 (5 neighbor-rows x 2
// halves, SGPR base + per-lane voffset) followed by s_waitcnt vmcnt(0) INSIDE
// the same asm. All destination registers are defined by this asm, so every
// use is ordered after the waitcnt -- race-free by construction (R4 lesson:
// separate load/waitcnt asm statements are not).
// ---------------------------------------------------------------------------
#define GATHER5x2(d0,d1,d2,d3,d4,d5,d6,d7,d8,d9, o0,o1,o2,o3,o4, base)      \
    asm volatile(                                                            \
        "global_load_dwordx4 %0, %10, %15 offset:0\n\t"                      \
        "global_load_dwordx4 %1, %10, %15 offset:16\n\t"                     \
        "global_load_dwordx4 %2, %11, %15 offset:0\n\t"                      \
        "global_load_dwordx4 %3, %11, %15 offset:16\n\t"                     \
        "global_load_dwordx4 %4, %12, %15 offset:0\n\t"                      \
        "global_load_dwordx4 %5, %12, %15 offset:16\n\t"                     \
        "global_load_dwordx4 %6, %13, %15 offset:0\n\t"                      \
        "global_load_dwordx4 %7, %13, %15 offset:16\n\t"                     \
        "global_load_dwordx4 %8, %14, %15 offset:0\n\t"                      \
        "global_load_dwordx4 %9, %14, %15 offset:16\n\t"                     \
        "s_waitcnt vmcnt(0)"                                                 \
        : "=&v"(d0), "=&v"(d1), "=&v"(d2), "=&v"(d3), "=&v"(d4),             \
          "=&v"(d5), "=&v"(d6), "=&v"(d7), "=&v"(d8), "=&v"(d9)              \
        : "v"(o0), "v"(o1), "v"(o2), "v"(o3), "v"(o4), "s"(base)             \
        : "memory")

// 10 independent rows, one dwordx4 each (k_block1: lane covers 4 floats).
#define GATHER10x1(d0,d1,d2,d3,d4,d5,d6,d7,d8,d9,                            \
                   o0,o1,o2,o3,o4,o5,o6,o7,o8,o9, base)                      \
    asm volatile(                                                            \
        "global_load_dwordx4 %0, %10, %20 offset:0\n\t"                      \
        "global_load_dwordx4 %1, %11, %20 offset:0\n\t"                      \
        "global_load_dwordx4 %2, %12, %20 offset:0\n\t"                      \
        "global_load_dwordx4 %3, %13, %20 offset:0\n\t"                      \
        "global_load_dwordx4 %4, %14, %20 offset:0\n\t"                      \
        "global_load_dwordx4 %5, %15, %20 offset:0\n\t"                      \
        "global_load_dwordx4 %6, %16, %20 offset:0\n\t"                      \
        "global_load_dwordx4 %7, %17, %20 offset:0\n\t"                      \
        "global_load_dwordx4 %8, %18, %20 offset:0\n\t"                      \
        "global_load_dwordx4 %9, %19, %20 offset:0\n\t"                      \
        "s_waitcnt vmcnt(0)"                                                 \
        : "=&v"(d0), "=&v"(d1), "=&v"(d2), "=&v"(d3), "=&v"(d4),             \
          "=&v"(d5), "=&v"(d6), "=&v"(d7), "=&v"(d8), "=&v"(d9)              \
        : "v"(o0), "v"(o1), "v"(o2), "v"(o3), "v"(o4),                       \
          "v"(o5), "v"(o6), "v"(o7), "v"(o8), "v"(o9), "s"(base)             \
        : "memory")

// ---------------------------------------------------------------------------
// Kernel 1: fused block 0.   [16 nodes/block, 32 KB LDS, 2560 blocks]
//   agg = mean_k(embed[nbr0] - h0_hist[nbr0]) + agg_h0
//   h   = agg @ W1 + b1                      (512 -> 128)
//   h1p = concat(h, relu(h)) - h1_hist       -> ws [N1, 256]
// ---------------------------------------------------------------------------
__global__ __launch_bounds__(256) void k_block0(
    const float* __restrict__ embed, const float* __restrict__ h0_hist,
    const float* __restrict__ h1_hist, const float* __restrict__ agg_h0,
    const float* __restrict__ W1, const float* __restrict__ b1,
    const int* __restrict__ nbr0, float* __restrict__ h1p)
{
    __shared__ float A[NB][IN];          // 32 KB aggregated-activation tile
    const int t = threadIdx.x;
    const int wave = t >> 6;
    const int lane = t & 63;
    const int base_node = blockIdx.x * NB;

    const uint64_t be = (uint64_t)embed;
    const uint64_t bg = (uint64_t)h0_hist;
    const uint32_t lane_byte = (uint32_t)lane * 32u;   // lane covers 8 floats

    // ---- phase 1: gather + mean + add agg_h0 (wave handles 4 nodes) ----
    #pragma unroll 1
    for (int i = 0; i < NB / 4; ++i) {
        const int nl = wave * (NB / 4) + i;
        const int node = base_node + nl;
        const int nb = node * KF;
        float4 acc0 = f4_zero(), acc1 = f4_zero();

        int idx[KF];
        #pragma unroll
        for (int j = 0; j < KF; ++j) idx[j] = nbr0[nb + j];

        #pragma unroll 1
        for (int c = 0; c < 2; ++c) {            // 2 chunks x 5 neighbors
            uint32_t v0 = (uint32_t)idx[c * 5 + 0] * (uint32_t)(IN * 4) + lane_byte;
            uint32_t v1 = (uint32_t)idx[c * 5 + 1] * (uint32_t)(IN * 4) + lane_byte;
            uint32_t v2 = (uint32_t)idx[c * 5 + 2] * (uint32_t)(IN * 4) + lane_byte;
            uint32_t v3 = (uint32_t)idx[c * 5 + 3] * (uint32_t)(IN * 4) + lane_byte;
            uint32_t v4 = (uint32_t)idx[c * 5 + 4] * (uint32_t)(IN * 4) + lane_byte;

            float4 e0, e1, e2, e3, e4, e5, e6, e7, e8, e9;
            GATHER5x2(e0, e1, e2, e3, e4, e5, e6, e7, e8, e9,
                      v0, v1, v2, v3, v4, be);
            acc0.x += e0.x + e2.x + e4.x + e6.x + e8.x;
            acc0.y += e0.y + e2.y + e4.y + e6.y + e8.y;
            acc0.z += e0.z + e2.z + e4.z + e6.z + e8.z;
            acc0.w += e0.w + e2.w + e4.w + e6.w + e8.w;
            acc1.x += e1.x + e3.x + e5.x + e7.x + e9.x;
            acc1.y += e1.y + e3.y + e5.y + e7.y + e9.y;
            acc1.z += e1.z + e3.z + e5.z + e7.z + e9.z;
            acc1.w += e1.w + e3.w + e5.w + e7.w + e9.w;

            float4 g0, g1, g2, g3, g4, g5, g6, g7, g8, g9;
            GATHER5x2(g0, g1, g2, g3, g4, g5, g6, g7, g8, g9,
                      v0, v1, v2, v3, v4, bg);
            acc0.x -= g0.x + g2.x + g4.x + g6.x + g8.x;
            acc0.y -= g0.y + g2.y + g4.y + g6.y + g8.y;
            acc0.z -= g0.z + g2.z + g4.z + g6.z + g8.z;
            acc0.w -= g0.w + g2.w + g4.w + g6.w + g8.w;
            acc1.x -= g1.x + g3.x + g5.x + g7.x + g9.x;
            acc1.y -= g1.y + g3.y + g5.y + g7.y + g9.y;
            acc1.z -= g1.z + g3.z + g5.z + g7.z + g9.z;
            acc1.w -= g1.w + g3.w + g5.w + g7.w + g9.w;
        }

        const float s = 1.0f / (float)KF;
        const int col = lane * 8;
        const float4* ah = (const float4*)(agg_h0 + (size_t)node * IN + col);
        const float4 a0 = ah[0], a1 = ah[1];
        float4 r0, r1;
        r0.x = acc0.x * s + a0.x; r0.y = acc0.y * s + a0.y;
        r0.z = acc0.z * s + a0.z; r0.w = acc0.w * s + a0.w;
        r1.x = acc1.x * s + a1.x; r1.y = acc1.y * s + a1.y;
        r1.z = acc1.z * s + a1.z; r1.w = acc1.w * s + a1.w;
        *(float4*)&A[nl][col]     = r0;
        *(float4*)&A[nl][col + 4] = r1;
    }
    __syncthreads();

    // ---- phase 2: GEMV 512 -> 128 + bias + concat/relu - h1_hist ----
    // (verbatim from R2, which passed)
    const int c0 = (t & 31) * 4;   // output col group (covers 128)
    const int rg = t >> 5;         // row group 0..7 (2 rows each -> 16)
    float4 acc[2];
    acc[0] = f4_zero(); acc[1] = f4_zero();

    #pragma unroll 4
    for (int k = 0; k < IN; ++k) {
        const float4 w = *(const float4*)&W1[k * HID + c0];
        #pragma unroll
        for (int i = 0; i < 2; ++i) {
            const float a = A[rg * 2 + i][k];
            acc[i].x += a * w.x; acc[i].y += a * w.y;
            acc[i].z += a * w.z; acc[i].w += a * w.w;
        }
    }

    const float4 bb = *(const float4*)&b1[c0];
    #pragma unroll
    for (int i = 0; i < 2; ++i) {
        const int node = base_node + rg * 2 + i;
        float4 h;
        h.x = acc[i].x + bb.x; h.y = acc[i].y + bb.y;
        h.z = acc[i].z + bb.z; h.w = acc[i].w + bb.w;
        const float4 hh0 = *(const float4*)&h1_hist[node * (2 * HID) + c0];
        const float4 hh1 = *(const float4*)&h1_hist[node * (2 * HID) + HID + c0];
        float4 o0, o1;
        o0.x = h.x - hh0.x; o0.y = h.y - hh0.y;
        o0.z = h.z - hh0.z; o0.w = h.w - hh0.w;
        o1.x = fmaxf(h.x, 0.f) - hh1.x; o1.y = fmaxf(h.y, 0.f) - hh1.y;
        o1.z = fmaxf(h.z, 0.f) - hh1.z; o1.w = fmaxf(h.w, 0.f) - hh1.w;
        *(float4*)&h1p[node * (2 * HID) + c0]       = o0;
        *(float4*)&h1p[node * (2 * HID) + HID + c0] = o1;
    }
}

// ---------------------------------------------------------------------------
// Kernel 2: fused block 1.   [8 nodes/block, 512 blocks]
//   agg = mean_k(h1p[nbr1]) + agg_h1 ; out = agg @ W2 + b2   (256 -> 64)
// ---------------------------------------------------------------------------
__global__ __launch_bounds__(256) void k_block1(
    const float* __restrict__ h1p, const float* __restrict__ agg_h1,
    const float* __restrict__ W2, const float* __restrict__ b2,
    const int* __restrict__ nbr1, float* __restrict__ out)
{
    __shared__ float B[8][2 * HID + 4];   // pad: kill bank alias on phase-2 reads
    const int t = threadIdx.x;
    const int wave = t >> 6;
    const int lane = t & 63;
    const int base_node = blockIdx.x * 8;
    const uint64_t bh = (uint64_t)h1p;
    const uint32_t lane_byte = (uint32_t)lane * 16u;   // lane covers 4 floats

    #pragma unroll 1
    for (int i = 0; i < 2; ++i) {
        const int nl = wave * 2 + i;
        const int node = base_node + nl;
        const int nb = node * KF;

        uint32_t o[KF];
        #pragma unroll
        for (int j = 0; j < KF; ++j)
            o[j] = (uint32_t)nbr1[nb + j] * (uint32_t)(2 * HID * 4) + lane_byte;

        float4 v0, v1, v2, v3, v4, v5, v6, v7, v8, v9;
        GATHER10x1(v0, v1, v2, v3, v4, v5, v6, v7, v8, v9,
                   o[0], o[1], o[2], o[3], o[4],
                   o[5], o[6], o[7], o[8], o[9], bh);

        float4 acc;
        acc.x = v0.x + v1.x + v2.x + v3.x + v4.x + v5.x + v6.x + v7.x + v8.x + v9.x;
        acc.y = v0.y + v1.y + v2.y + v3.y + v4.y + v5.y + v6.y + v7.y + v8.y + v9.y;
        acc.z = v0.z + v1.z + v2.z + v3.z + v4.z + v5.z + v6.z + v7.z + v8.z + v9.z;
        acc.w = v0.w + v1.w + v2.w + v3.w + v4.w + v5.w + v6.w + v7.w + v8.w + v9.w;

        const float s = 1.0f / (float)KF;
        const int col = lane * 4;
        const float4 g = *(const float4*)&agg_h1[(size_t)node * (2 * HID) + col];
        float4 r;
        r.x = acc.x * s + g.x; r.y = acc.y * s + g.y;
        r.z = acc.z * s + g.z; r.w = acc.w * s + g.w;
        *(float4*)&B[nl][col] = r;
    }
    __syncthreads();

    // ---- phase 2: GEMV 256 -> 64 + bias (verbatim from R3, which passed) ----
    const int r = t >> 5;          // node row 0..7
    const int c0 = (t & 31) * 2;   // col pair (covers 64)
    float2 acc = make_float2(0.f, 0.f);
    #pragma unroll 4
    for (int k = 0; k < 2 * HID; ++k) {
        const float a = B[r][k];
        const float2 w = *(const float2*)&W2[k * NCLS + c0];
        acc.x += a * w.x; acc.y += a * w.y;
    }
    const float2 bb = *(const float2*)&b2[c0];
    float2 o;
    o.x = acc.x + bb.x; o.y = acc.y + bb.y;
    const int node = base_node + r;
    *(float2*)&out[node * NCLS + c0] = o;
}

extern "C" void kernel_launch(void* const* d_in, const int* in_sizes, int n_in,
                              void* d_out, int out_size, void* d_ws, size_t ws_size,
                              hipStream_t stream) {
    const float* embed   = (const float*)d_in[0];
    const float* h0_hist = (const float*)d_in[1];
    const float* h1_hist = (const float*)d_in[2];
    const float* agg_h0  = (const float*)d_in[3];
    const float* agg_h1  = (const float*)d_in[4];
    const float* W1      = (const float*)d_in[5];
    const float* b1      = (const float*)d_in[6];
    const float* W2      = (const float*)d_in[7];
    const float* b2      = (const float*)d_in[8];
    const int*   nbr0    = (const int*)d_in[9];
    const int*   nbr1    = (const int*)d_in[10];
    float* out = (float*)d_out;

    // ws: h1p [N1, 256] f32 = 41.9 MB
    float* h1p = (float*)d_ws;

    k_block0<<<N1 / NB, 256, 0, stream>>>(embed, h0_hist, h1_hist, agg_h0,
                                          W1, b1, nbr0, h1p);
    k_block1<<<N2 / 8, 256, 0, stream>>>(h1p, agg_h1, W2, b2, nbr1, out);
}